// Round 13
// baseline (326.991 us; speedup 1.0000x reference)
//
#include <hip/hip_runtime.h>
#include <hip/hip_fp16.h>
#include <type_traits>

// ---------------------------------------------------------------------------
// 3-layer GCN (PyG GCNConv, add_self_loops=False) on MI355X.
// Pipeline (8 launches):
//   memset(deg)
//   fused1: 3 gemm1-blocks : 4 count-workers (static %8 partitions)
//   scan1 ; scan3' (block-sum prefix folded in)
//   fused2: 3 scale-blocks : 2 fill-workers
//   AG1: agg(Hh)+BN1+ReLU ->LDS-> gemm(W2) -> Hh2 fp16 (dinv-scaled)
//   AG2: agg(Hh2)+BN2+ReLU ->LDS-> gemm(W3) -> Hh3 fp16 (dinv-scaled)
//   agg3: agg(Hh3)+b3 -> d_out fp32
// Round-12 insight: inputs stay L3-resident across replays; pipeline is
// L3/latency bound and ~35us sits in launch gaps + Gh round-trips. The AG
// fusion keeps the 64x64 agg tile in LDS through the next GEMM (no global
// round-trip, fp32 precision preserved into the gemm).
// ---------------------------------------------------------------------------

struct half4 { __half2 a, b; };
struct half8 { half4 lo, hi; };
typedef int iv4 __attribute__((ext_vector_type(4)));
typedef short sv8 __attribute__((ext_vector_type(8)));

constexpr int SCAN_T = 256;
constexpr int SCAN_E = 8;
constexpr int SCAN_B = SCAN_T * SCAN_E;
constexpr int NPART = 8;
constexpr int ECHUNK = 2048;
constexpr int NWORK = 2048;
constexpr int WSTRIDE = NWORK / 8;

// ---------------- edge-phase bodies ----------------

__device__ __forceinline__ void count_chunk(int c, int lo, int hi,
                                            const int* __restrict__ dst,
                                            int* __restrict__ deg, int E) {
  const int base = c * ECHUNK + threadIdx.x * 4;
#pragma unroll
  for (int h = 0; h < 2; ++h) {
    int e = base + h * 1024;
    if (e + 3 < E) {
      iv4 d4 = __builtin_nontemporal_load(reinterpret_cast<const iv4*>(&dst[e]));
      if (d4.x >= lo && d4.x < hi) atomicAdd(&deg[d4.x], 1);
      if (d4.y >= lo && d4.y < hi) atomicAdd(&deg[d4.y], 1);
      if (d4.z >= lo && d4.z < hi) atomicAdd(&deg[d4.z], 1);
      if (d4.w >= lo && d4.w < hi) atomicAdd(&deg[d4.w], 1);
    } else {
      for (int j = 0; j < 4; ++j) {
        int ee = e + j;
        if (ee < E) {
          int d = dst[ee];
          if (d >= lo && d < hi) atomicAdd(&deg[d], 1);
        }
      }
    }
  }
}

__device__ __forceinline__ void fill_chunk(int c, int lo, int hi,
                                           const int* __restrict__ src,
                                           const int* __restrict__ dst,
                                           int* __restrict__ fillc,
                                           int* __restrict__ csr_src, int E) {
  const int base = c * ECHUNK + threadIdx.x * 4;
#pragma unroll
  for (int h = 0; h < 2; ++h) {
    int e = base + h * 1024;
    if (e + 3 < E) {
      iv4 d4 = __builtin_nontemporal_load(reinterpret_cast<const iv4*>(&dst[e]));
      iv4 s4 = __builtin_nontemporal_load(reinterpret_cast<const iv4*>(&src[e]));
      if (d4.x >= lo && d4.x < hi) csr_src[atomicAdd(&fillc[d4.x], 1)] = s4.x;
      if (d4.y >= lo && d4.y < hi) csr_src[atomicAdd(&fillc[d4.y], 1)] = s4.y;
      if (d4.z >= lo && d4.z < hi) csr_src[atomicAdd(&fillc[d4.z], 1)] = s4.z;
      if (d4.w >= lo && d4.w < hi) csr_src[atomicAdd(&fillc[d4.w], 1)] = s4.w;
    } else {
      for (int j = 0; j < 4; ++j) {
        int ee = e + j;
        if (ee < E) {
          int d = dst[ee];
          if (d >= lo && d < hi) csr_src[atomicAdd(&fillc[d], 1)] = src[ee];
        }
      }
    }
  }
}

__device__ __forceinline__ void scale_body(int bid, __half* __restrict__ Hh,
                                           const float* __restrict__ dinv, int N) {
  int idx = bid * 256 + threadIdx.x;
  if (idx >= N * 8) return;
  float s = dinv[idx >> 3];
  sv8 raw = __builtin_nontemporal_load(reinterpret_cast<sv8*>(&Hh[(size_t)idx * 8]));
  half8 v = *reinterpret_cast<half8*>(&raw);
  float2 f;
  f = __half22float2(v.lo.a); v.lo.a = __floats2half2_rn(f.x * s, f.y * s);
  f = __half22float2(v.lo.b); v.lo.b = __floats2half2_rn(f.x * s, f.y * s);
  f = __half22float2(v.hi.a); v.hi.a = __floats2half2_rn(f.x * s, f.y * s);
  f = __half22float2(v.hi.b); v.hi.b = __floats2half2_rn(f.x * s, f.y * s);
  __builtin_nontemporal_store(*reinterpret_cast<sv8*>(&v),
                              reinterpret_cast<sv8*>(&Hh[(size_t)idx * 8]));
}

// ---------------- scans ----------------

__global__ __launch_bounds__(SCAN_T) void k_scan1(const int* __restrict__ deg,
                                                  int* __restrict__ pre,
                                                  int* __restrict__ bsum, int N) {
  __shared__ int ls[SCAN_T];
  int t = threadIdx.x;
  int base = blockIdx.x * SCAN_B + t * SCAN_E;
  int v[SCAN_E];
  int s = 0;
#pragma unroll
  for (int j = 0; j < SCAN_E; ++j) {
    int idx = base + j;
    v[j] = (idx < N) ? deg[idx] : 0;
    s += v[j];
  }
  ls[t] = s;
  __syncthreads();
  for (int off = 1; off < SCAN_T; off <<= 1) {
    int x = 0;
    if (t >= off) x = ls[t - off];
    __syncthreads();
    ls[t] += x;
    __syncthreads();
  }
  if (t == SCAN_T - 1) bsum[blockIdx.x] = ls[t];
  int run = (t > 0) ? ls[t - 1] : 0;
#pragma unroll
  for (int j = 0; j < SCAN_E; ++j) {
    int idx = base + j;
    if (idx < N) pre[idx] = run;
    run += v[j];
  }
}

// rowptr += prefix(bsum); fillc = rowptr; dinv.  bsum prefix computed locally
// (nb<=256 entries, thread-0 serial — merges old scan2).
__global__ __launch_bounds__(256) void k_scan3(int* __restrict__ rowptr,
                                               int* __restrict__ fillc,
                                               const int* __restrict__ bsum,
                                               const int* __restrict__ deg,
                                               float* __restrict__ dinv,
                                               int N, int E, int nb) {
  __shared__ int pb[256];
  if (threadIdx.x == 0) {
    int run = 0;
    for (int j = 0; j < nb; ++j) { pb[j] = run; run += bsum[j]; }
  }
  __syncthreads();
  int i = blockIdx.x * 256 + threadIdx.x;
  if (i < N) {
    int r = rowptr[i] + pb[i / SCAN_B];
    rowptr[i] = r;
    fillc[i] = r;
    int d = deg[i];
    dinv[i] = (d > 0) ? rsqrtf((float)d) : 0.f;
  }
  if (i == 0) rowptr[N] = E;
}

// ---------------- GEMM inner (shared by gemm1 and AG kernels) ----------------
// 16 fp32 acc per thread; X from LDS (padded stride XP), W from LDS.
template <int F, int KC, int XP>
__device__ __forceinline__ void gemm_inner(const float* __restrict__ xr,
                                           const float* __restrict__ wb,
                                           float4& a0, float4& a1,
                                           float4& a2, float4& a3) {
#pragma unroll 2
  for (int k = 0; k < KC; k += 4) {
    float4 w0 = *reinterpret_cast<const float4*>(&wb[(k + 0) * F]);
    float4 w1 = *reinterpret_cast<const float4*>(&wb[(k + 1) * F]);
    float4 w2 = *reinterpret_cast<const float4*>(&wb[(k + 2) * F]);
    float4 w3 = *reinterpret_cast<const float4*>(&wb[(k + 3) * F]);
    float4 x0 = *reinterpret_cast<const float4*>(&xr[0 * XP + k]);
    float4 x1 = *reinterpret_cast<const float4*>(&xr[1 * XP + k]);
    float4 x2 = *reinterpret_cast<const float4*>(&xr[2 * XP + k]);
    float4 x3 = *reinterpret_cast<const float4*>(&xr[3 * XP + k]);
    a0.x = fmaf(x0.x, w0.x, a0.x); a0.y = fmaf(x0.x, w0.y, a0.y);
    a0.z = fmaf(x0.x, w0.z, a0.z); a0.w = fmaf(x0.x, w0.w, a0.w);
    a1.x = fmaf(x1.x, w0.x, a1.x); a1.y = fmaf(x1.x, w0.y, a1.y);
    a1.z = fmaf(x1.x, w0.z, a1.z); a1.w = fmaf(x1.x, w0.w, a1.w);
    a2.x = fmaf(x2.x, w0.x, a2.x); a2.y = fmaf(x2.x, w0.y, a2.y);
    a2.z = fmaf(x2.x, w0.z, a2.z); a2.w = fmaf(x2.x, w0.w, a2.w);
    a3.x = fmaf(x3.x, w0.x, a3.x); a3.y = fmaf(x3.x, w0.y, a3.y);
    a3.z = fmaf(x3.x, w0.z, a3.z); a3.w = fmaf(x3.x, w0.w, a3.w);

    a0.x = fmaf(x0.y, w1.x, a0.x); a0.y = fmaf(x0.y, w1.y, a0.y);
    a0.z = fmaf(x0.y, w1.z, a0.z); a0.w = fmaf(x0.y, w1.w, a0.w);
    a1.x = fmaf(x1.y, w1.x, a1.x); a1.y = fmaf(x1.y, w1.y, a1.y);
    a1.z = fmaf(x1.y, w1.z, a1.z); a1.w = fmaf(x1.y, w1.w, a1.w);
    a2.x = fmaf(x2.y, w1.x, a2.x); a2.y = fmaf(x2.y, w1.y, a2.y);
    a2.z = fmaf(x2.y, w1.z, a2.z); a2.w = fmaf(x2.y, w1.w, a2.w);
    a3.x = fmaf(x3.y, w1.x, a3.x); a3.y = fmaf(x3.y, w1.y, a3.y);
    a3.z = fmaf(x3.y, w1.z, a3.z); a3.w = fmaf(x3.y, w1.w, a3.w);

    a0.x = fmaf(x0.z, w2.x, a0.x); a0.y = fmaf(x0.z, w2.y, a0.y);
    a0.z = fmaf(x0.z, w2.z, a0.z); a0.w = fmaf(x0.z, w2.w, a0.w);
    a1.x = fmaf(x1.z, w2.x, a1.x); a1.y = fmaf(x1.z, w2.y, a1.y);
    a1.z = fmaf(x1.z, w2.z, a1.z); a1.w = fmaf(x1.z, w2.w, a1.w);
    a2.x = fmaf(x2.z, w2.x, a2.x); a2.y = fmaf(x2.z, w2.y, a2.y);
    a2.z = fmaf(x2.z, w2.z, a2.z); a2.w = fmaf(x2.z, w2.w, a2.w);
    a3.x = fmaf(x3.z, w2.x, a3.x); a3.y = fmaf(x3.z, w2.y, a3.y);
    a3.z = fmaf(x3.z, w2.z, a3.z); a3.w = fmaf(x3.z, w2.w, a3.w);

    a0.x = fmaf(x0.w, w3.x, a0.x); a0.y = fmaf(x0.w, w3.y, a0.y);
    a0.z = fmaf(x0.w, w3.z, a0.z); a0.w = fmaf(x0.w, w3.w, a0.w);
    a1.x = fmaf(x1.w, w3.x, a1.x); a1.y = fmaf(x1.w, w3.y, a1.y);
    a1.z = fmaf(x1.w, w3.z, a1.z); a1.w = fmaf(x1.w, w3.w, a1.w);
    a2.x = fmaf(x2.w, w3.x, a2.x); a2.y = fmaf(x2.w, w3.y, a2.y);
    a2.z = fmaf(x2.w, w3.z, a2.z); a2.w = fmaf(x2.w, w3.w, a2.w);
    a3.x = fmaf(x3.w, w3.x, a3.x); a3.y = fmaf(x3.w, w3.y, a3.y);
    a3.z = fmaf(x3.w, w3.z, a3.z); a3.w = fmaf(x3.w, w3.w, a3.w);
  }
}

// gemm1 body: X fp32 global -> Hh fp16 (unscaled)
__device__ __forceinline__ void gemm1_body(int bid, const float* __restrict__ X,
                                           const float* __restrict__ W,
                                           __half* __restrict__ Hh, int N) {
  constexpr int K = 128, F = 64, KC = 64, NC = 2, XP = KC + 4;
  __shared__ float Wl[KC * F];
  __shared__ float Xl[64 * XP];
  const int t = threadIdx.x;
  const int row0 = bid * 64;
  const int cg = t % 16, rg = t / 16;
  float4 a0 = make_float4(0.f, 0.f, 0.f, 0.f);
  float4 a1 = make_float4(0.f, 0.f, 0.f, 0.f);
  float4 a2 = make_float4(0.f, 0.f, 0.f, 0.f);
  float4 a3 = make_float4(0.f, 0.f, 0.f, 0.f);
  for (int c = 0; c < NC; ++c) {
    __syncthreads();
    for (int i = t; i < KC * F / 4; i += 256)
      reinterpret_cast<float4*>(Wl)[i] =
          reinterpret_cast<const float4*>(W + c * KC * F)[i];
    for (int i = t; i < 64 * KC / 4; i += 256) {
      int r = (i * 4) / KC, col = (i * 4) % KC;
      int row = row0 + r;
      float4 v = make_float4(0.f, 0.f, 0.f, 0.f);
      if (row < N)
        v = *reinterpret_cast<const float4*>(&X[(size_t)row * K + c * KC + col]);
      *reinterpret_cast<float4*>(&Xl[r * XP + col]) = v;
    }
    __syncthreads();
    gemm_inner<F, KC, XP>(&Xl[rg * 4 * XP], &Wl[cg * 4], a0, a1, a2, a3);
  }
  const int col = cg * 4;
  const int row = row0 + rg * 4;
#pragma unroll
  for (int r = 0; r < 4; ++r) {
    if (row + r < N) {
      float4 v = (r == 0) ? a0 : (r == 1) ? a1 : (r == 2) ? a2 : a3;
      half4 o;
      o.a = __floats2half2_rn(v.x, v.y);
      o.b = __floats2half2_rn(v.z, v.w);
      *reinterpret_cast<half4*>(&Hh[(size_t)(row + r) * F + col]) = o;
    }
  }
}

// fused1: slots of 7 = 3 gemm1 blocks + 4 count workers.
__global__ __launch_bounds__(256) void k_fused1(const float* __restrict__ X,
                                                const float* __restrict__ W,
                                                __half* __restrict__ Hh, int N,
                                                int gemmBlocks,
                                                const int* __restrict__ dst,
                                                int* __restrict__ deg,
                                                int E, int PS, int nchunks) {
  const int bid = (int)blockIdx.x;
  const int slot = bid / 7, r = bid % 7;
  if (r < 3) {
    int g = slot * 3 + r;
    if (g < gemmBlocks) gemm1_body(g, X, W, Hh, N);
    return;
  }
  int widx = slot * 4 + (r - 3);
  if (widx >= NWORK) return;
  const int p = widx & 7;
  const int lo = p * PS, hi = lo + PS;
  for (int c = widx >> 3; c < nchunks; c += WSTRIDE)
    count_chunk(c, lo, hi, dst, deg, E);
}

// fused2: slots of 5 = 3 scale blocks + 2 fill workers.
__global__ __launch_bounds__(256) void k_fused2(const int* __restrict__ src,
                                                const int* __restrict__ dst,
                                                int* __restrict__ fillc,
                                                int* __restrict__ csr_src,
                                                int E, int PS, int nchunks,
                                                __half* __restrict__ Hh,
                                                const float* __restrict__ dinv,
                                                int N, int scaleBlocks) {
  const int bid = (int)blockIdx.x;
  const int slot = bid / 5, r = bid % 5;
  if (r < 3) {
    int sb = slot * 3 + r;
    if (sb < scaleBlocks) scale_body(sb, Hh, dinv, N);
    return;
  }
  int widx = slot * 2 + (r - 3);
  if (widx >= NWORK) return;
  const int p = widx & 7;
  const int lo = p * PS, hi = lo + PS;
  for (int c = widx >> 3; c < nchunks; c += WSTRIDE)
    fill_chunk(c, lo, hi, src, dst, fillc, csr_src, E);
}

// ---------------- fused agg + gemm ----------------
// Block = 64 nodes. Phase 1: 4 waves x 16 nodes aggregate H (F=64 fp16) with
// BN+ReLU epilogue -> Xl (fp32, LDS). Phase 2: gemm Xl @ W(64xFO) -> Hout fp16
// scaled by dinv (ready for next layer's gather).
template <int FO>
__global__ __launch_bounds__(256) void k_aggemm(const __half* __restrict__ H,
                                                const float* __restrict__ W,
                                                __half* __restrict__ Hout,
                                                const int* __restrict__ rowptr,
                                                const int* __restrict__ csr_src,
                                                const float* __restrict__ dinv,
                                                const float* __restrict__ bias,
                                                const float* __restrict__ gam,
                                                const float* __restrict__ bet,
                                                const float* __restrict__ mu,
                                                const float* __restrict__ var,
                                                int N) {
  constexpr int K = 64, XP = K + 4;
  __shared__ float Xl[64 * XP];
  __shared__ float Wl[K * FO];
  const int t = threadIdx.x;
  const int row0 = (int)blockIdx.x * 64;

  for (int i = t; i < K * FO / 4; i += 256)
    reinterpret_cast<float4*>(Wl)[i] = reinterpret_cast<const float4*>(W)[i];

  // phase 1: aggregation (each wave owns 16 rows)
  const int wv = t >> 6, lane = t & 63;
  const int g = lane >> 4, gl = lane & 15;
  for (int it = 0; it < 16; ++it) {
    const int lr = wv * 16 + it;          // local row
    const int node = row0 + lr;
    float4 a0 = make_float4(0.f, 0.f, 0.f, 0.f);
    float4 a1 = make_float4(0.f, 0.f, 0.f, 0.f);
    if (node < N) {
      int p0 = rowptr[node], p1 = rowptr[node + 1];
      int p = p0 + g;
      for (; p + 4 < p1; p += 8) {
        int s0 = csr_src[p];
        int s1 = csr_src[p + 4];
        half4 h0 = *reinterpret_cast<const half4*>(&H[(size_t)s0 * 64 + gl * 4]);
        half4 h1 = *reinterpret_cast<const half4*>(&H[(size_t)s1 * 64 + gl * 4]);
        float2 l0 = __half22float2(h0.a), u0 = __half22float2(h0.b);
        float2 l1 = __half22float2(h1.a), u1 = __half22float2(h1.b);
        a0.x += l0.x; a0.y += l0.y; a0.z += u0.x; a0.w += u0.y;
        a1.x += l1.x; a1.y += l1.y; a1.z += u1.x; a1.w += u1.y;
      }
      if (p < p1) {
        int s0 = csr_src[p];
        half4 h0 = *reinterpret_cast<const half4*>(&H[(size_t)s0 * 64 + gl * 4]);
        float2 l0 = __half22float2(h0.a), u0 = __half22float2(h0.b);
        a0.x += l0.x; a0.y += l0.y; a0.z += u0.x; a0.w += u0.y;
      }
    }
    a0.x += a1.x; a0.y += a1.y; a0.z += a1.z; a0.w += a1.w;
#pragma unroll
    for (int off = 16; off <= 32; off <<= 1) {
      a0.x += __shfl_xor(a0.x, off);
      a0.y += __shfl_xor(a0.y, off);
      a0.z += __shfl_xor(a0.z, off);
      a0.w += __shfl_xor(a0.w, off);
    }
    if (g == 0) {
      int f = gl * 4;
      float4 y = make_float4(0.f, 0.f, 0.f, 0.f);
      if (node < N) {
        float di = dinv[node];
        y.x = fmaf(di, a0.x, bias[f + 0]);
        y.y = fmaf(di, a0.y, bias[f + 1]);
        y.z = fmaf(di, a0.z, bias[f + 2]);
        y.w = fmaf(di, a0.w, bias[f + 3]);
        y.x = fmaxf((y.x - mu[f + 0]) * rsqrtf(var[f + 0] + 1e-5f) * gam[f + 0] + bet[f + 0], 0.f);
        y.y = fmaxf((y.y - mu[f + 1]) * rsqrtf(var[f + 1] + 1e-5f) * gam[f + 1] + bet[f + 1], 0.f);
        y.z = fmaxf((y.z - mu[f + 2]) * rsqrtf(var[f + 2] + 1e-5f) * gam[f + 2] + bet[f + 2], 0.f);
        y.w = fmaxf((y.w - mu[f + 3]) * rsqrtf(var[f + 3] + 1e-5f) * gam[f + 3] + bet[f + 3], 0.f);
      }
      *reinterpret_cast<float4*>(&Xl[lr * XP + f]) = y;
    }
  }
  __syncthreads();

  // phase 2: gemm Xl(64xK) @ Wl(KxFO) -> Hout fp16 scaled by dinv
  constexpr int CG = FO / 4;
  const int cg = t % CG, rg = t / CG;
  if (rg < 16) {
    float4 a0 = make_float4(0.f, 0.f, 0.f, 0.f);
    float4 a1 = make_float4(0.f, 0.f, 0.f, 0.f);
    float4 a2 = make_float4(0.f, 0.f, 0.f, 0.f);
    float4 a3 = make_float4(0.f, 0.f, 0.f, 0.f);
    gemm_inner<FO, K, XP>(&Xl[rg * 4 * XP], &Wl[cg * 4], a0, a1, a2, a3);
    const int col = cg * 4;
    const int row = row0 + rg * 4;
#pragma unroll
    for (int r = 0; r < 4; ++r) {
      if (row + r < N) {
        float4 v = (r == 0) ? a0 : (r == 1) ? a1 : (r == 2) ? a2 : a3;
        float s = dinv[row + r];
        half4 o;
        o.a = __floats2half2_rn(v.x * s, v.y * s);
        o.b = __floats2half2_rn(v.z * s, v.w * s);
        *reinterpret_cast<half4*>(&Hout[(size_t)(row + r) * FO + col]) = o;
      }
    }
  }
}

// ---------------- final aggregation (F=40, fp32 out, +bias only) ----------------
__global__ __launch_bounds__(256) void k_agg3(const __half* __restrict__ H,
                                              float* __restrict__ G,
                                              const int* __restrict__ rowptr,
                                              const int* __restrict__ csr_src,
                                              const float* __restrict__ dinv,
                                              const float* __restrict__ bias,
                                              int N) {
  constexpr int F = 40;
  constexpr int LPG = F / 4;  // 10
  int node = (blockIdx.x * 256 + threadIdx.x) >> 6;
  int lane = threadIdx.x & 63;
  if (node >= N) return;
  int g = lane >> 4, gl = lane & 15;
  bool active = gl < LPG;
  int p0 = rowptr[node], p1 = rowptr[node + 1];
  float4 a0 = make_float4(0.f, 0.f, 0.f, 0.f);
  float4 a1 = make_float4(0.f, 0.f, 0.f, 0.f);
  int p = p0 + g;
  for (; p + 4 < p1; p += 8) {
    int s0 = csr_src[p];
    int s1 = csr_src[p + 4];
    if (active) {
      half4 h0 = *reinterpret_cast<const half4*>(&H[(size_t)s0 * F + gl * 4]);
      half4 h1 = *reinterpret_cast<const half4*>(&H[(size_t)s1 * F + gl * 4]);
      float2 l0 = __half22float2(h0.a), u0 = __half22float2(h0.b);
      float2 l1 = __half22float2(h1.a), u1 = __half22float2(h1.b);
      a0.x += l0.x; a0.y += l0.y; a0.z += u0.x; a0.w += u0.y;
      a1.x += l1.x; a1.y += l1.y; a1.z += u1.x; a1.w += u1.y;
    }
  }
  if (p < p1) {
    int s0 = csr_src[p];
    if (active) {
      half4 h0 = *reinterpret_cast<const half4*>(&H[(size_t)s0 * F + gl * 4]);
      float2 l0 = __half22float2(h0.a), u0 = __half22float2(h0.b);
      a0.x += l0.x; a0.y += l0.y; a0.z += u0.x; a0.w += u0.y;
    }
  }
  a0.x += a1.x; a0.y += a1.y; a0.z += a1.z; a0.w += a1.w;
#pragma unroll
  for (int off = 16; off <= 32; off <<= 1) {
    a0.x += __shfl_xor(a0.x, off);
    a0.y += __shfl_xor(a0.y, off);
    a0.z += __shfl_xor(a0.z, off);
    a0.w += __shfl_xor(a0.w, off);
  }
  if (g == 0 && active) {
    int f = gl * 4;
    float di = dinv[node];
    float4 y;
    y.x = fmaf(di, a0.x, bias[f + 0]);
    y.y = fmaf(di, a0.y, bias[f + 1]);
    y.z = fmaf(di, a0.z, bias[f + 2]);
    y.w = fmaf(di, a0.w, bias[f + 3]);
    *reinterpret_cast<float4*>(&G[(size_t)node * F + f]) = y;
  }
}

extern "C" void kernel_launch(void* const* d_in, const int* in_sizes, int n_in,
                              void* d_out, int out_size, void* d_ws, size_t ws_size,
                              hipStream_t stream) {
  const float* x  = (const float*)d_in[0];
  const int*   ei = (const int*)d_in[1];
  const float* W1 = (const float*)d_in[2];
  const float* b1 = (const float*)d_in[3];
  const float* W2 = (const float*)d_in[4];
  const float* b2 = (const float*)d_in[5];
  const float* W3 = (const float*)d_in[6];
  const float* b3 = (const float*)d_in[7];
  const float* g1 = (const float*)d_in[8];
  const float* be1 = (const float*)d_in[9];
  const float* m1 = (const float*)d_in[10];
  const float* v1 = (const float*)d_in[11];
  const float* g2 = (const float*)d_in[12];
  const float* be2 = (const float*)d_in[13];
  const float* m2 = (const float*)d_in[14];
  const float* v2 = (const float*)d_in[15];

  const int N = in_sizes[0] / 128;  // 100000
  const int E = in_sizes[1] / 2;    // 1000000
  const int* src = ei;
  const int* dst = ei + E;

  char* w = (char*)d_ws;
  size_t off = 0;
  auto take = [&](size_t bytes) -> void* {
    void* p = w + off;
    off += (bytes + 511) & ~size_t(511);
    return p;
  };
  int*    deg     = (int*)take((size_t)N * 4);
  size_t  zeroB   = off;                     // deg zeroed
  int*    fillc   = (int*)take((size_t)N * 4);
  int*    rowptr  = (int*)take(((size_t)N + 1) * 4);
  float*  dinv    = (float*)take((size_t)N * 4);
  int*    bsum    = (int*)take((size_t)SCAN_T * 4);
  int*    csr_src = (int*)take((size_t)E * 4);
  __half* Hh      = (__half*)take((size_t)N * 64 * 2);  // also holds Hh3 (N x 40)
  __half* Hh2     = (__half*)take((size_t)N * 64 * 2);
  if (off > ws_size) return;

  const int nb = (N + SCAN_B - 1) / SCAN_B;           // 49
  const int PS = (N + NPART - 1) / NPART;             // 12500
  const int nchunks = (E + ECHUNK - 1) / ECHUNK;      // 489
  const int gemm1Blocks = (N + 63) / 64;              // 1563
  const int scaleBlocks = (N * 8 + 255) / 256;        // 3125
  const int f1Slots = ((gemm1Blocks + 2) / 3) > (NWORK / 4) ? ((gemm1Blocks + 2) / 3)
                                                            : (NWORK / 4);
  const int f1Grid = f1Slots * 7;
  const int f2Slots = ((scaleBlocks + 2) / 3) > (NWORK / 2) ? ((scaleBlocks + 2) / 3)
                                                            : (NWORK / 2);
  const int f2Grid = f2Slots * 5;
  const int agBlocks = (N + 63) / 64;                 // 1563

  hipMemsetAsync(d_ws, 0, zeroB, stream);
  k_fused1<<<f1Grid, 256, 0, stream>>>(x, W1, Hh, N, gemm1Blocks,
                                       dst, deg, E, PS, nchunks);
  k_scan1<<<nb, SCAN_T, 0, stream>>>(deg, rowptr, bsum, N);
  k_scan3<<<(N + 255) / 256, 256, 0, stream>>>(rowptr, fillc, bsum, deg, dinv,
                                               N, E, nb);
  k_fused2<<<f2Grid, 256, 0, stream>>>(src, dst, fillc, csr_src, E, PS, nchunks,
                                       Hh, dinv, N, scaleBlocks);

  // AG1: agg(Hh)+BN1+ReLU -> gemm W2 -> Hh2 (fp16, dinv-scaled)
  k_aggemm<64><<<agBlocks, 256, 0, stream>>>(Hh, W2, Hh2, rowptr, csr_src, dinv,
                                             b1, g1, be1, m1, v1, N);
  // AG2: agg(Hh2)+BN2+ReLU -> gemm W3 -> Hh (fp16 N x 40, dinv-scaled)
  k_aggemm<40><<<agBlocks, 256, 0, stream>>>(Hh2, W3, Hh, rowptr, csr_src, dinv,
                                             b2, g2, be2, m2, v2, N);
  // final aggregation
  k_agg3<<<(N + 3) / 4, 256, 0, stream>>>(Hh, (float*)d_out, rowptr, csr_src,
                                          dinv, b3, N);
}

// Round 14
// 285.033 us; speedup vs baseline: 1.1472x; 1.1472x over previous
//
#include <hip/hip_runtime.h>
#include <hip/hip_fp16.h>
#include <type_traits>

// ---------------------------------------------------------------------------
// 3-layer GCN (PyG GCNConv, add_self_loops=False) on MI355X.
// Pipeline (10 dispatches, round-12 structure + scan2 merged into scan3):
//   memset(deg)
//   fused1: 3 gemm1-blocks : 4 count-workers (static %8 partitions)
//   scan1 ; scan3' (bsum prefix in-block)
//   fused2: 3 scale-blocks : 2 fill-workers
//   agg1 -> Gh fp16 ; gemm2 -> Hh ; agg2 -> Gh ; gemm3 -> Hh40 ; agg3 -> out
// Round-13 lesson: fusing the latency-bound gather into gemm-shaped blocks
// collapses TLP (92us) — keep agg at 1 wave/node, 25000 blocks.
// This round: KC=32 K-chunking -> LDS 33KB->17.4KB -> 8 blocks/CU (was 4),
// for gemm1/2/3 (fused1's count workers double co-residency too).
// ---------------------------------------------------------------------------

struct half4 { __half2 a, b; };
struct half8 { half4 lo, hi; };
typedef int iv4 __attribute__((ext_vector_type(4)));
typedef short sv8 __attribute__((ext_vector_type(8)));

constexpr int SCAN_T = 256;
constexpr int SCAN_E = 8;
constexpr int SCAN_B = SCAN_T * SCAN_E;
constexpr int NPART = 8;
constexpr int ECHUNK = 2048;
constexpr int NWORK = 2048;
constexpr int WSTRIDE = NWORK / 8;

// ---------------- edge-phase bodies ----------------

__device__ __forceinline__ void count_chunk(int c, int lo, int hi,
                                            const int* __restrict__ dst,
                                            int* __restrict__ deg, int E) {
  const int base = c * ECHUNK + threadIdx.x * 4;
#pragma unroll
  for (int h = 0; h < 2; ++h) {
    int e = base + h * 1024;
    if (e + 3 < E) {
      iv4 d4 = __builtin_nontemporal_load(reinterpret_cast<const iv4*>(&dst[e]));
      if (d4.x >= lo && d4.x < hi) atomicAdd(&deg[d4.x], 1);
      if (d4.y >= lo && d4.y < hi) atomicAdd(&deg[d4.y], 1);
      if (d4.z >= lo && d4.z < hi) atomicAdd(&deg[d4.z], 1);
      if (d4.w >= lo && d4.w < hi) atomicAdd(&deg[d4.w], 1);
    } else {
      for (int j = 0; j < 4; ++j) {
        int ee = e + j;
        if (ee < E) {
          int d = dst[ee];
          if (d >= lo && d < hi) atomicAdd(&deg[d], 1);
        }
      }
    }
  }
}

__device__ __forceinline__ void fill_chunk(int c, int lo, int hi,
                                           const int* __restrict__ src,
                                           const int* __restrict__ dst,
                                           int* __restrict__ fillc,
                                           int* __restrict__ csr_src, int E) {
  const int base = c * ECHUNK + threadIdx.x * 4;
#pragma unroll
  for (int h = 0; h < 2; ++h) {
    int e = base + h * 1024;
    if (e + 3 < E) {
      iv4 d4 = __builtin_nontemporal_load(reinterpret_cast<const iv4*>(&dst[e]));
      iv4 s4 = __builtin_nontemporal_load(reinterpret_cast<const iv4*>(&src[e]));
      if (d4.x >= lo && d4.x < hi) csr_src[atomicAdd(&fillc[d4.x], 1)] = s4.x;
      if (d4.y >= lo && d4.y < hi) csr_src[atomicAdd(&fillc[d4.y], 1)] = s4.y;
      if (d4.z >= lo && d4.z < hi) csr_src[atomicAdd(&fillc[d4.z], 1)] = s4.z;
      if (d4.w >= lo && d4.w < hi) csr_src[atomicAdd(&fillc[d4.w], 1)] = s4.w;
    } else {
      for (int j = 0; j < 4; ++j) {
        int ee = e + j;
        if (ee < E) {
          int d = dst[ee];
          if (d >= lo && d < hi) csr_src[atomicAdd(&fillc[d], 1)] = src[ee];
        }
      }
    }
  }
}

__device__ __forceinline__ void scale_body(int bid, __half* __restrict__ Hh,
                                           const float* __restrict__ dinv, int N) {
  int idx = bid * 256 + threadIdx.x;
  if (idx >= N * 8) return;
  float s = dinv[idx >> 3];
  sv8 raw = __builtin_nontemporal_load(reinterpret_cast<sv8*>(&Hh[(size_t)idx * 8]));
  half8 v = *reinterpret_cast<half8*>(&raw);
  float2 f;
  f = __half22float2(v.lo.a); v.lo.a = __floats2half2_rn(f.x * s, f.y * s);
  f = __half22float2(v.lo.b); v.lo.b = __floats2half2_rn(f.x * s, f.y * s);
  f = __half22float2(v.hi.a); v.hi.a = __floats2half2_rn(f.x * s, f.y * s);
  f = __half22float2(v.hi.b); v.hi.b = __floats2half2_rn(f.x * s, f.y * s);
  __builtin_nontemporal_store(*reinterpret_cast<sv8*>(&v),
                              reinterpret_cast<sv8*>(&Hh[(size_t)idx * 8]));
}

// ---------------- scans ----------------

__global__ __launch_bounds__(SCAN_T) void k_scan1(const int* __restrict__ deg,
                                                  int* __restrict__ pre,
                                                  int* __restrict__ bsum, int N) {
  __shared__ int ls[SCAN_T];
  int t = threadIdx.x;
  int base = blockIdx.x * SCAN_B + t * SCAN_E;
  int v[SCAN_E];
  int s = 0;
#pragma unroll
  for (int j = 0; j < SCAN_E; ++j) {
    int idx = base + j;
    v[j] = (idx < N) ? deg[idx] : 0;
    s += v[j];
  }
  ls[t] = s;
  __syncthreads();
  for (int off = 1; off < SCAN_T; off <<= 1) {
    int x = 0;
    if (t >= off) x = ls[t - off];
    __syncthreads();
    ls[t] += x;
    __syncthreads();
  }
  if (t == SCAN_T - 1) bsum[blockIdx.x] = ls[t];
  int run = (t > 0) ? ls[t - 1] : 0;
#pragma unroll
  for (int j = 0; j < SCAN_E; ++j) {
    int idx = base + j;
    if (idx < N) pre[idx] = run;
    run += v[j];
  }
}

// rowptr += prefix(bsum); fillc = rowptr; dinv.  (scan2 merged: bsum prefix
// computed locally by thread 0, nb<=256.)
__global__ __launch_bounds__(256) void k_scan3(int* __restrict__ rowptr,
                                               int* __restrict__ fillc,
                                               const int* __restrict__ bsum,
                                               const int* __restrict__ deg,
                                               float* __restrict__ dinv,
                                               int N, int E, int nb) {
  __shared__ int pb[256];
  if (threadIdx.x == 0) {
    int run = 0;
    for (int j = 0; j < nb; ++j) { pb[j] = run; run += bsum[j]; }
  }
  __syncthreads();
  int i = blockIdx.x * 256 + threadIdx.x;
  if (i < N) {
    int r = rowptr[i] + pb[i / SCAN_B];
    rowptr[i] = r;
    fillc[i] = r;
    int d = deg[i];
    dinv[i] = (d > 0) ? rsqrtf((float)d) : 0.f;
  }
  if (i == 0) rowptr[N] = E;
}

// ---------------- GEMM body (KC=32 chunks -> ~17.4KB LDS, 8 blocks/CU) ------
template <int K, int F, typename Tin, bool SCALE>
__device__ __forceinline__ void gemm_body(int bid, const Tin* __restrict__ X,
                                          const float* __restrict__ W,
                                          const float* __restrict__ dinv,
                                          __half* __restrict__ Hh, int N) {
  constexpr int CG = F / 4;            // 16 (F=64) or 10 (F=40)
  constexpr int RG = 256 / CG;         // 16 or 25
  constexpr int ROWS = RG * 4;         // 64 or 100
  constexpr int KC = 32;
  constexpr int NC = K / KC;           // 4 (K=128) or 2 (K=64)
  constexpr int XP = KC + 4;
  __shared__ float Wl[KC * F];
  __shared__ float Xl[ROWS * XP];

  const int t = threadIdx.x;
  const int row0 = bid * ROWS;
  const int cg = t % CG;
  const int rg = t / CG;
  float4 a0 = make_float4(0.f, 0.f, 0.f, 0.f);
  float4 a1 = make_float4(0.f, 0.f, 0.f, 0.f);
  float4 a2 = make_float4(0.f, 0.f, 0.f, 0.f);
  float4 a3 = make_float4(0.f, 0.f, 0.f, 0.f);

  for (int c = 0; c < NC; ++c) {
    __syncthreads();  // previous chunk reads done
    for (int i = t; i < KC * F / 4; i += 256)
      reinterpret_cast<float4*>(Wl)[i] =
          reinterpret_cast<const float4*>(W + c * KC * F)[i];
    for (int i = t; i < ROWS * KC / 4; i += 256) {
      int r = (i * 4) / KC, col = (i * 4) % KC;
      int row = row0 + r;
      float4 v = make_float4(0.f, 0.f, 0.f, 0.f);
      if (row < N) {
        if constexpr (std::is_same<Tin, float>::value) {
          v = *reinterpret_cast<const float4*>(&X[(size_t)row * K + c * KC + col]);
        } else {
          half4 hv = *reinterpret_cast<const half4*>(&X[(size_t)row * K + c * KC + col]);
          float2 lo = __half22float2(hv.a), hi = __half22float2(hv.b);
          v = make_float4(lo.x, lo.y, hi.x, hi.y);
        }
      }
      *reinterpret_cast<float4*>(&Xl[r * XP + col]) = v;
    }
    __syncthreads();
    if (rg < RG) {
      const float* xr = &Xl[rg * 4 * XP];
      const float* wb = &Wl[cg * 4];
#pragma unroll 2
      for (int k = 0; k < KC; k += 4) {
        float4 w0 = *reinterpret_cast<const float4*>(&wb[(k + 0) * F]);
        float4 w1 = *reinterpret_cast<const float4*>(&wb[(k + 1) * F]);
        float4 w2 = *reinterpret_cast<const float4*>(&wb[(k + 2) * F]);
        float4 w3 = *reinterpret_cast<const float4*>(&wb[(k + 3) * F]);
        float4 x0 = *reinterpret_cast<const float4*>(&xr[0 * XP + k]);
        float4 x1 = *reinterpret_cast<const float4*>(&xr[1 * XP + k]);
        float4 x2 = *reinterpret_cast<const float4*>(&xr[2 * XP + k]);
        float4 x3 = *reinterpret_cast<const float4*>(&xr[3 * XP + k]);
        a0.x = fmaf(x0.x, w0.x, a0.x); a0.y = fmaf(x0.x, w0.y, a0.y);
        a0.z = fmaf(x0.x, w0.z, a0.z); a0.w = fmaf(x0.x, w0.w, a0.w);
        a1.x = fmaf(x1.x, w0.x, a1.x); a1.y = fmaf(x1.x, w0.y, a1.y);
        a1.z = fmaf(x1.x, w0.z, a1.z); a1.w = fmaf(x1.x, w0.w, a1.w);
        a2.x = fmaf(x2.x, w0.x, a2.x); a2.y = fmaf(x2.x, w0.y, a2.y);
        a2.z = fmaf(x2.x, w0.z, a2.z); a2.w = fmaf(x2.x, w0.w, a2.w);
        a3.x = fmaf(x3.x, w0.x, a3.x); a3.y = fmaf(x3.x, w0.y, a3.y);
        a3.z = fmaf(x3.x, w0.z, a3.z); a3.w = fmaf(x3.x, w0.w, a3.w);

        a0.x = fmaf(x0.y, w1.x, a0.x); a0.y = fmaf(x0.y, w1.y, a0.y);
        a0.z = fmaf(x0.y, w1.z, a0.z); a0.w = fmaf(x0.y, w1.w, a0.w);
        a1.x = fmaf(x1.y, w1.x, a1.x); a1.y = fmaf(x1.y, w1.y, a1.y);
        a1.z = fmaf(x1.y, w1.z, a1.z); a1.w = fmaf(x1.y, w1.w, a1.w);
        a2.x = fmaf(x2.y, w1.x, a2.x); a2.y = fmaf(x2.y, w1.y, a2.y);
        a2.z = fmaf(x2.y, w1.z, a2.z); a2.w = fmaf(x2.y, w1.w, a2.w);
        a3.x = fmaf(x3.y, w1.x, a3.x); a3.y = fmaf(x3.y, w1.y, a3.y);
        a3.z = fmaf(x3.y, w1.z, a3.z); a3.w = fmaf(x3.y, w1.w, a3.w);

        a0.x = fmaf(x0.z, w2.x, a0.x); a0.y = fmaf(x0.z, w2.y, a0.y);
        a0.z = fmaf(x0.z, w2.z, a0.z); a0.w = fmaf(x0.z, w2.w, a0.w);
        a1.x = fmaf(x1.z, w2.x, a1.x); a1.y = fmaf(x1.z, w2.y, a1.y);
        a1.z = fmaf(x1.z, w2.z, a1.z); a1.w = fmaf(x1.z, w2.w, a1.w);
        a2.x = fmaf(x2.z, w2.x, a2.x); a2.y = fmaf(x2.z, w2.y, a2.y);
        a2.z = fmaf(x2.z, w2.z, a2.z); a2.w = fmaf(x2.z, w2.w, a2.w);
        a3.x = fmaf(x3.z, w2.x, a3.x); a3.y = fmaf(x3.z, w2.y, a3.y);
        a3.z = fmaf(x3.z, w2.z, a3.z); a3.w = fmaf(x3.z, w2.w, a3.w);

        a0.x = fmaf(x0.w, w3.x, a0.x); a0.y = fmaf(x0.w, w3.y, a0.y);
        a0.z = fmaf(x0.w, w3.z, a0.z); a0.w = fmaf(x0.w, w3.w, a0.w);
        a1.x = fmaf(x1.w, w3.x, a1.x); a1.y = fmaf(x1.w, w3.y, a1.y);
        a1.z = fmaf(x1.w, w3.z, a1.z); a1.w = fmaf(x1.w, w3.w, a1.w);
        a2.x = fmaf(x2.w, w3.x, a2.x); a2.y = fmaf(x2.w, w3.y, a2.y);
        a2.z = fmaf(x2.w, w3.z, a2.z); a2.w = fmaf(x2.w, w3.w, a2.w);
        a3.x = fmaf(x3.w, w3.x, a3.x); a3.y = fmaf(x3.w, w3.y, a3.y);
        a3.z = fmaf(x3.w, w3.z, a3.z); a3.w = fmaf(x3.w, w3.w, a3.w);
      }
    }
  }

  if (rg < RG) {
    const int col = cg * 4;
    const int row = row0 + rg * 4;
#pragma unroll
    for (int r = 0; r < 4; ++r) {
      if (row + r < N) {
        float4 v = (r == 0) ? a0 : (r == 1) ? a1 : (r == 2) ? a2 : a3;
        float s = 1.f;
        if constexpr (SCALE) s = dinv[row + r];
        half4 o;
        o.a = __floats2half2_rn(v.x * s, v.y * s);
        o.b = __floats2half2_rn(v.z * s, v.w * s);
        *reinterpret_cast<half4*>(&Hh[(size_t)(row + r) * F + col]) = o;
      }
    }
  }
}

template <int K, int F>
__global__ __launch_bounds__(256) void k_gemm_h(const __half* __restrict__ X,
                                                const float* __restrict__ W,
                                                const float* __restrict__ dinv,
                                                __half* __restrict__ Hh, int N) {
  gemm_body<K, F, __half, true>(blockIdx.x, X, W, dinv, Hh, N);
}

// fused1: slots of 7 = 3 gemm1 blocks + 4 count workers (static partitions).
__global__ __launch_bounds__(256) void k_fused1(const float* __restrict__ X,
                                                const float* __restrict__ W,
                                                __half* __restrict__ Hh, int N,
                                                int gemmBlocks,
                                                const int* __restrict__ dst,
                                                int* __restrict__ deg,
                                                int E, int PS, int nchunks) {
  const int bid = (int)blockIdx.x;
  const int slot = bid / 7, r = bid % 7;
  if (r < 3) {
    int g = slot * 3 + r;
    if (g < gemmBlocks) gemm_body<128, 64, float, false>(g, X, W, nullptr, Hh, N);
    return;
  }
  int widx = slot * 4 + (r - 3);
  if (widx >= NWORK) return;
  const int p = widx & 7;
  const int lo = p * PS, hi = lo + PS;
  for (int c = widx >> 3; c < nchunks; c += WSTRIDE)
    count_chunk(c, lo, hi, dst, deg, E);
}

// fused2: slots of 5 = 3 scale blocks + 2 fill workers (static partitions).
__global__ __launch_bounds__(256) void k_fused2(const int* __restrict__ src,
                                                const int* __restrict__ dst,
                                                int* __restrict__ fillc,
                                                int* __restrict__ csr_src,
                                                int E, int PS, int nchunks,
                                                __half* __restrict__ Hh,
                                                const float* __restrict__ dinv,
                                                int N, int scaleBlocks) {
  const int bid = (int)blockIdx.x;
  const int slot = bid / 5, r = bid % 5;
  if (r < 3) {
    int sb = slot * 3 + r;
    if (sb < scaleBlocks) scale_body(sb, Hh, dinv, N);
    return;
  }
  int widx = slot * 2 + (r - 3);
  if (widx >= NWORK) return;
  const int p = widx & 7;
  const int lo = p * PS, hi = lo + PS;
  for (int c = widx >> 3; c < nchunks; c += WSTRIDE)
    fill_chunk(c, lo, hi, src, dst, fillc, csr_src, E);
}

// ---------------- aggregation (1 wave/node) ----------------
template <int F, bool BNR, typename Tout>
__global__ __launch_bounds__(256) void k_agg(const __half* __restrict__ H,
                                             Tout* __restrict__ G,
                                             const int* __restrict__ rowptr,
                                             const int* __restrict__ csr_src,
                                             const float* __restrict__ dinv,
                                             const float* __restrict__ bias,
                                             const float* __restrict__ gam,
                                             const float* __restrict__ bet,
                                             const float* __restrict__ mu,
                                             const float* __restrict__ var, int N) {
  constexpr int LPG = F / 4;
  int node = (blockIdx.x * 256 + threadIdx.x) >> 6;
  int lane = threadIdx.x & 63;
  if (node >= N) return;
  int g = lane >> 4, gl = lane & 15;
  bool active = gl < LPG;
  int p0 = rowptr[node], p1 = rowptr[node + 1];
  float4 a0 = make_float4(0.f, 0.f, 0.f, 0.f);
  float4 a1 = make_float4(0.f, 0.f, 0.f, 0.f);
  int p = p0 + g;
  for (; p + 4 < p1; p += 8) {
    int s0 = csr_src[p];
    int s1 = csr_src[p + 4];
    if (active) {
      half4 h0 = *reinterpret_cast<const half4*>(&H[(size_t)s0 * F + gl * 4]);
      half4 h1 = *reinterpret_cast<const half4*>(&H[(size_t)s1 * F + gl * 4]);
      float2 l0 = __half22float2(h0.a), u0 = __half22float2(h0.b);
      float2 l1 = __half22float2(h1.a), u1 = __half22float2(h1.b);
      a0.x += l0.x; a0.y += l0.y; a0.z += u0.x; a0.w += u0.y;
      a1.x += l1.x; a1.y += l1.y; a1.z += u1.x; a1.w += u1.y;
    }
  }
  if (p < p1) {
    int s0 = csr_src[p];
    if (active) {
      half4 h0 = *reinterpret_cast<const half4*>(&H[(size_t)s0 * F + gl * 4]);
      float2 l0 = __half22float2(h0.a), u0 = __half22float2(h0.b);
      a0.x += l0.x; a0.y += l0.y; a0.z += u0.x; a0.w += u0.y;
    }
  }
  a0.x += a1.x; a0.y += a1.y; a0.z += a1.z; a0.w += a1.w;
#pragma unroll
  for (int off = 16; off <= 32; off <<= 1) {
    a0.x += __shfl_xor(a0.x, off);
    a0.y += __shfl_xor(a0.y, off);
    a0.z += __shfl_xor(a0.z, off);
    a0.w += __shfl_xor(a0.w, off);
  }
  if (g == 0 && active) {
    int f = gl * 4;
    float di = dinv[node];
    float4 y;
    y.x = fmaf(di, a0.x, bias[f + 0]);
    y.y = fmaf(di, a0.y, bias[f + 1]);
    y.z = fmaf(di, a0.z, bias[f + 2]);
    y.w = fmaf(di, a0.w, bias[f + 3]);
    if (BNR) {
      y.x = fmaxf((y.x - mu[f + 0]) * rsqrtf(var[f + 0] + 1e-5f) * gam[f + 0] + bet[f + 0], 0.f);
      y.y = fmaxf((y.y - mu[f + 1]) * rsqrtf(var[f + 1] + 1e-5f) * gam[f + 1] + bet[f + 1], 0.f);
      y.z = fmaxf((y.z - mu[f + 2]) * rsqrtf(var[f + 2] + 1e-5f) * gam[f + 2] + bet[f + 2], 0.f);
      y.w = fmaxf((y.w - mu[f + 3]) * rsqrtf(var[f + 3] + 1e-5f) * gam[f + 3] + bet[f + 3], 0.f);
    }
    if constexpr (std::is_same<Tout, __half>::value) {
      half4 o;
      o.a = __floats2half2_rn(y.x, y.y);
      o.b = __floats2half2_rn(y.z, y.w);
      *reinterpret_cast<half4*>(&G[(size_t)node * F + f]) = o;
    } else {
      *reinterpret_cast<float4*>(&G[(size_t)node * F + f]) = y;
    }
  }
}

extern "C" void kernel_launch(void* const* d_in, const int* in_sizes, int n_in,
                              void* d_out, int out_size, void* d_ws, size_t ws_size,
                              hipStream_t stream) {
  const float* x  = (const float*)d_in[0];
  const int*   ei = (const int*)d_in[1];
  const float* W1 = (const float*)d_in[2];
  const float* b1 = (const float*)d_in[3];
  const float* W2 = (const float*)d_in[4];
  const float* b2 = (const float*)d_in[5];
  const float* W3 = (const float*)d_in[6];
  const float* b3 = (const float*)d_in[7];
  const float* g1 = (const float*)d_in[8];
  const float* be1 = (const float*)d_in[9];
  const float* m1 = (const float*)d_in[10];
  const float* v1 = (const float*)d_in[11];
  const float* g2 = (const float*)d_in[12];
  const float* be2 = (const float*)d_in[13];
  const float* m2 = (const float*)d_in[14];
  const float* v2 = (const float*)d_in[15];

  const int N = in_sizes[0] / 128;  // 100000
  const int E = in_sizes[1] / 2;    // 1000000
  const int* src = ei;
  const int* dst = ei + E;

  char* w = (char*)d_ws;
  size_t off = 0;
  auto take = [&](size_t bytes) -> void* {
    void* p = w + off;
    off += (bytes + 511) & ~size_t(511);
    return p;
  };
  int*    deg     = (int*)take((size_t)N * 4);
  size_t  zeroB   = off;                     // deg zeroed
  int*    fillc   = (int*)take((size_t)N * 4);
  int*    rowptr  = (int*)take(((size_t)N + 1) * 4);
  float*  dinv    = (float*)take((size_t)N * 4);
  int*    bsum    = (int*)take((size_t)SCAN_T * 4);
  int*    csr_src = (int*)take((size_t)E * 4);
  __half* Hh      = (__half*)take((size_t)N * 64 * 2);
  __half* Gh      = (__half*)take((size_t)N * 64 * 2);
  if (off > ws_size) return;

  const int nb = (N + SCAN_B - 1) / SCAN_B;           // 49
  const int PS = (N + NPART - 1) / NPART;             // 12500
  const int nchunks = (E + ECHUNK - 1) / ECHUNK;      // 489
  const int gemm1Blocks = (N + 63) / 64;              // 1563
  const int scaleBlocks = (N * 8 + 255) / 256;        // 3125
  const int f1Slots = ((gemm1Blocks + 2) / 3) > (NWORK / 4) ? ((gemm1Blocks + 2) / 3)
                                                            : (NWORK / 4);
  const int f1Grid = f1Slots * 7;
  const int f2Slots = ((scaleBlocks + 2) / 3) > (NWORK / 2) ? ((scaleBlocks + 2) / 3)
                                                            : (NWORK / 2);
  const int f2Grid = f2Slots * 5;

  hipMemsetAsync(d_ws, 0, zeroB, stream);
  k_fused1<<<f1Grid, 256, 0, stream>>>(x, W1, Hh, N, gemm1Blocks,
                                       dst, deg, E, PS, nchunks);
  k_scan1<<<nb, SCAN_T, 0, stream>>>(deg, rowptr, bsum, N);
  k_scan3<<<(N + 255) / 256, 256, 0, stream>>>(rowptr, fillc, bsum, deg, dinv,
                                               N, E, nb);
  k_fused2<<<f2Grid, 256, 0, stream>>>(src, dst, fillc, csr_src, E, PS, nchunks,
                                       Hh, dinv, N, scaleBlocks);

  // layer 1 aggregation -> Gh (fp16)
  k_agg<64, true, __half><<<(N + 3) / 4, 256, 0, stream>>>(
      Hh, Gh, rowptr, csr_src, dinv, b1, g1, be1, m1, v1, N);
  // layer 2
  k_gemm_h<64, 64><<<(N + 63) / 64, 256, 0, stream>>>(Gh, W2, dinv, Hh, N);
  k_agg<64, true, __half><<<(N + 3) / 4, 256, 0, stream>>>(
      Hh, Gh, rowptr, csr_src, dinv, b2, g2, be2, m2, v2, N);
  // output layer
  k_gemm_h<64, 40><<<(N + 99) / 100, 256, 0, stream>>>(Gh, W3, dinv, Hh, N);
  k_agg<40, false, float><<<(N + 3) / 4, 256, 0, stream>>>(
      Hh, (float*)d_out, rowptr, csr_src, dinv, b3, nullptr, nullptr, nullptr,
      nullptr, N);
}